// Round 6
// baseline (528.633 us; speedup 1.0000x reference)
//
#include <hip/hip_runtime.h>
#include <hip/hip_cooperative_groups.h>

namespace cg = cooperative_groups;

#define NSP   4096
#define HW    512
#define TEMP  0.08838834764831845f  // 128^-0.5
#define MAXE  640
#define GRID  1024                  // needs only 4 blocks/CU co-resident (256 CUs)
#define NTHR  256
#define TOTT  (GRID * NTHR)         // 262144 threads

struct AttnS {                       // per-node scratch, 8336 B
    unsigned int words[128];
    int   pfx[128];
    int   midx[MAXE];
    float wts[MAXE];
    float q0s[32];
    float4 redv[4][32];
    float redw[4];
};
struct GathS {                       // 17024 B
    float tile[32][132];
    int   sseg[32];
};
constexpr size_t SMEM_BYTES = (2 * sizeof(AttnS) > sizeof(GathS)) ? 2 * sizeof(AttnS) : sizeof(GathS);

// ========================= fused cooperative kernel ========================
//  P0: zero adjacency mask || Wfused = Wv @ Wout
//  P1: adjacency bitmask || Q0/K0 (l2-normed) + V' = x@Wf   (virtual ids, 2 passes)
//  P2: sparse masked softmax-attention -> final node table (+bias)
//  P3: pixel gather via LDS transpose, 128B-aligned full-line HBM stores
__global__ void __launch_bounds__(NTHR, 4) fused_all(
    const int* __restrict__ seg, const float* __restrict__ spf,
    const float* __restrict__ wqkv, const float* __restrict__ wout,
    const float* __restrict__ bout, float* __restrict__ out,
    unsigned int* __restrict__ mask, float* __restrict__ Q0,
    float* __restrict__ K0, float* __restrict__ Vp,
    float* __restrict__ fin, float* __restrict__ Wf)
{
    cg::grid_group grid = cg::this_grid();
    __shared__ __align__(16) char smem[SMEM_BYTES];
    const int t   = threadIdx.x;
    const int tid = blockIdx.x * NTHR + t;           // 0..262143

    // ---------------- P0 ----------------
    if (tid < 131072) {                              // 2 MB mask as uint4
        ((uint4*)mask)[tid] = make_uint4(0u, 0u, 0u, 0u);
    } else if (tid < 147456) {                       // Wf[d][c], 128x128
        int gid = tid - 131072;
        int d = gid >> 7, c = gid & 127;
        float acc = 0.f;
#pragma unroll 8
        for (int k = 0; k < 128; ++k)
            acc += wqkv[d * 384 + 256 + k] * wout[k * 128 + c];
        Wf[d * 128 + c] = acc;
    }
    grid.sync();

    // ---------------- P1: 196608 QKV + 260100 adjacency work items ---------
    for (int vt = tid; vt < 456708; vt += TOTT) {
        if (vt < 196608) {                           // QKV: node n, col-group g
            int g = vt % 48, n = vt / 48;
            const float* wbase; int wstride; float* outp;
            if (g < 8)       { wbase = wqkv + g * 4;             wstride = 384; outp = Q0 + n * 32  + g * 4; }
            else if (g < 16) { wbase = wqkv + 128 + (g - 8) * 4; wstride = 384; outp = K0 + n * 32  + (g - 8) * 4; }
            else             { wbase = Wf + (g - 16) * 4;        wstride = 128; outp = Vp + n * 128 + (g - 16) * 4; }
            float4 acc = {0.f, 0.f, 0.f, 0.f};
#pragma unroll 8
            for (int d = 0; d < 128; ++d) {
                float x = spf[d * NSP + n];          // x[n][d] = spf[d][n]
                float4 w = *(const float4*)(wbase + d * wstride);
                acc.x += x * w.x; acc.y += x * w.y; acc.z += x * w.z; acc.w += x * w.w;
            }
            if (g < 16) {                            // 8-groups are 8-aligned in wave
                float s = acc.x * acc.x + acc.y * acc.y + acc.z * acc.z + acc.w * acc.w;
                s += __shfl_xor(s, 1); s += __shfl_xor(s, 2); s += __shfl_xor(s, 4);
                float inv = 1.0f / fmaxf(sqrtf(s), 1e-12f);
                acc.x *= inv; acc.y *= inv; acc.z *= inv; acc.w *= inv;
            }
            *(float4*)outp = acc;
        } else {
            int aid = vt - 196608;                   // adjacency window
            int i = aid / 510, j = aid - i * 510;
            const int* r = seg + i * HW + j;
            int a = r[0], b = r[1], c = r[HW], d = r[HW + 1];
            int mx = max(max(a, b), max(c, d));
            int mn = min(min(a, b), min(c, d));
            if (mx != mn) {
                atomicOr(&mask[mx * 128 + (mn >> 5)], 1u << (mn & 31));
                atomicOr(&mask[mn * 128 + (mx >> 5)], 1u << (mx & 31));
            }
        }
    }
    grid.sync();

    // ---------------- P2: attention, 2 iterations x 2 nodes per block ------
    for (int it = 0; it < 2; ++it) {
        if (it) __syncthreads();
        AttnS* A = ((AttnS*)smem) + (t >> 7);
        const int tt   = t & 127;
        const int n    = it * 2048 + blockIdx.x * 2 + (t >> 7);
        const int lane = t & 63;
        const int wid  = tt >> 6;

        unsigned int w = mask[n * 128 + tt];
        A->words[tt] = w;
        if (tt < 32) A->q0s[tt] = Q0[n * 32 + tt];
        int p = __popc(w);
#pragma unroll
        for (int off = 1; off < 64; off <<= 1) {     // wave inclusive scan
            int y = __shfl_up(p, off);
            if (lane >= off) p += y;
        }
        A->pfx[tt] = p;
        __syncthreads();
        if (wid == 1) A->pfx[tt] = p + A->pfx[63];
        __syncthreads();
        int E = min(A->pfx[127], MAXE);

        for (int e = tt; e < E; e += 128) {          // balanced edge extraction
            int lo = 0, hi = 127;
            while (lo < hi) { int mid = (lo + hi) >> 1; if (A->pfx[mid] > e) hi = mid; else lo = mid + 1; }
            int base = lo ? A->pfx[lo - 1] : 0;
            int r = e - base;
            unsigned int x = A->words[lo];
            for (int i = 0; i < r; ++i) x &= x - 1;  // r-th set bit
            int m = lo * 32 + (__ffs(x) - 1);
            const float4* kp = (const float4*)(K0 + m * 32);
            float s = 0.f;
#pragma unroll
            for (int i = 0; i < 8; ++i) {
                float4 kv = kp[i];
                s += A->q0s[i * 4 + 0] * kv.x + A->q0s[i * 4 + 1] * kv.y +
                     A->q0s[i * 4 + 2] * kv.z + A->q0s[i * 4 + 3] * kv.w;
            }
            A->wts[e]  = __expf(s * TEMP - 1.0f);    // diagonal score 1.0 = row max
            A->midx[e] = m;
        }
        __syncthreads();

        int cg_ = tt & 31, eg = tt >> 5;
        const float4* V4 = (const float4*)Vp;
        float4 acc = {0.f, 0.f, 0.f, 0.f};
        float wp = 0.f;
        int e = eg;
        for (; e + 4 < E; e += 8) {                  // 2 independent L2 streams
            float wa = A->wts[e];     int ma = A->midx[e];
            float wb = A->wts[e + 4]; int mb = A->midx[e + 4];
            float4 va = V4[ma * 32 + cg_];
            float4 vb = V4[mb * 32 + cg_];
            acc.x += wa * va.x + wb * vb.x; acc.y += wa * va.y + wb * vb.y;
            acc.z += wa * va.z + wb * vb.z; acc.w += wa * va.w + wb * vb.w;
            wp += wa + wb;
        }
        for (; e < E; e += 4) {
            float wt = A->wts[e];
            float4 v = V4[A->midx[e] * 32 + cg_];
            acc.x += wt * v.x; acc.y += wt * v.y; acc.z += wt * v.z; acc.w += wt * v.w;
            wp += wt;
        }
        A->redv[eg][cg_] = acc;
        if (cg_ == 0) A->redw[eg] = wp;
        __syncthreads();
        if (tt < 32) {
            float4 a0 = A->redv[0][tt], a1 = A->redv[1][tt], a2 = A->redv[2][tt], a3 = A->redv[3][tt];
            float wsum = 1.0f + A->redw[0] + A->redw[1] + A->redw[2] + A->redw[3];
            float4 vd = V4[n * 32 + tt];             // diagonal, weight e^0 = 1
            float4 bb = ((const float4*)bout)[tt];   // bias: softmax rows sum to 1
            float inv = 1.0f / wsum;
            float4 o;
            o.x = (a0.x + a1.x + a2.x + a3.x + vd.x) * inv + bb.x;
            o.y = (a0.y + a1.y + a2.y + a3.y + vd.y) * inv + bb.y;
            o.z = (a0.z + a1.z + a2.z + a3.z + vd.z) * inv + bb.z;
            o.w = (a0.w + a1.w + a2.w + a3.w + vd.w) * inv + bb.w;
            ((float4*)fin)[n * 32 + tt] = o;
        }
        __syncthreads();
    }
    grid.sync();

    // ---------------- P3: gather, 8 tiles of 32 px per block ----------------
    {
        GathS* G = (GathS*)smem;
        const float4* f4 = (const float4*)fin;
        for (int it = 0; it < 8; ++it) {
            int base = (it * GRID + blockIdx.x) * 32;
            if (it) __syncthreads();
            if (t < 32) G->sseg[t] = seg[base + t];
            __syncthreads();
            int c4 = t & 31, pr = t >> 5;            // phase A: node rows -> LDS
#pragma unroll
            for (int i = 0; i < 4; ++i) {
                int p = pr + 8 * i;
                float4 v = f4[G->sseg[p] * 32 + c4];
                *(float4*)&G->tile[p][c4 * 4] = v;
            }
            __syncthreads();
            int i4 = t & 7, ccb = t >> 3;            // phase B: 128B/plane lines
#pragma unroll
            for (int pass = 0; pass < 4; ++pass) {
                int cc = ccb + 32 * pass;
                float4 v;
                v.x = G->tile[4 * i4 + 0][cc];
                v.y = G->tile[4 * i4 + 1][cc];
                v.z = G->tile[4 * i4 + 2][cc];
                v.w = G->tile[4 * i4 + 3][cc];
                *(float4*)(out + (size_t)cc * (HW * HW) + base + 4 * i4) = v;
            }
        }
    }
}

// ========================= fallback: round-4 pipeline ======================
#define PREP_ZERO 512
#define PREP_WF 64
#define ADJ_BLOCKS 1017
#define QKV_BLOCKS 768

__global__ void __launch_bounds__(256) prep(
    unsigned int* __restrict__ mask, const float* __restrict__ wqkv,
    const float* __restrict__ wout, float* __restrict__ Wf) {
    int t = threadIdx.x;
    if (blockIdx.x < PREP_ZERO) {
        ((uint4*)mask)[blockIdx.x * 256 + t] = make_uint4(0u, 0u, 0u, 0u);
        return;
    }
    int gid = (blockIdx.x - PREP_ZERO) * 256 + t;
    int d = gid >> 7, c = gid & 127;
    float acc = 0.f;
#pragma unroll 8
    for (int k = 0; k < 128; ++k)
        acc += wqkv[d * 384 + 256 + k] * wout[k * 128 + c];
    Wf[d * 128 + c] = acc;
}

__global__ void __launch_bounds__(256) adj_qkv(
    const int* __restrict__ seg, unsigned int* __restrict__ mask,
    const float* __restrict__ spf, const float* __restrict__ wqkv,
    const float* __restrict__ Wf,
    float* __restrict__ Q0, float* __restrict__ K0, float* __restrict__ V) {
    int t = threadIdx.x;
    if (blockIdx.x < ADJ_BLOCKS) {
        int idx = blockIdx.x * 256 + t;
        if (idx >= 510 * 510) return;
        int i = idx / 510, j = idx - i * 510;
        const int* r = seg + i * HW + j;
        int a = r[0], b = r[1], c = r[HW], d = r[HW + 1];
        int mx = max(max(a, b), max(c, d));
        int mn = min(min(a, b), min(c, d));
        if (mx == mn) return;
        atomicOr(&mask[mx * 128 + (mn >> 5)], 1u << (mn & 31));
        atomicOr(&mask[mn * 128 + (mx >> 5)], 1u << (mx & 31));
        return;
    }
    int gid = (blockIdx.x - ADJ_BLOCKS) * 256 + t;
    int g = gid % 48;
    int n = gid / 48;
    const float* wbase; int wstride; float* outp;
    if (g < 8)       { wbase = wqkv + g * 4;               wstride = 384; outp = Q0 + n * 32  + g * 4; }
    else if (g < 16) { wbase = wqkv + 128 + (g - 8) * 4;   wstride = 384; outp = K0 + n * 32  + (g - 8) * 4; }
    else             { wbase = Wf + (g - 16) * 4;          wstride = 128; outp = V  + n * 128 + (g - 16) * 4; }
    float4 acc = {0.f, 0.f, 0.f, 0.f};
#pragma unroll 8
    for (int d = 0; d < 128; ++d) {
        float x = spf[d * NSP + n];
        float4 w = *(const float4*)(wbase + d * wstride);
        acc.x += x * w.x; acc.y += x * w.y; acc.z += x * w.z; acc.w += x * w.w;
    }
    if (g < 16) {
        float s = acc.x * acc.x + acc.y * acc.y + acc.z * acc.z + acc.w * acc.w;
        s += __shfl_xor(s, 1); s += __shfl_xor(s, 2); s += __shfl_xor(s, 4);
        float inv = 1.0f / fmaxf(sqrtf(s), 1e-12f);
        acc.x *= inv; acc.y *= inv; acc.z *= inv; acc.w *= inv;
    }
    *(float4*)outp = acc;
}

__global__ void __launch_bounds__(128) sparse_attn(
    const unsigned int* __restrict__ mask, const float* __restrict__ Q0,
    const float* __restrict__ K0, const float* __restrict__ V,
    const float* __restrict__ bout, float* __restrict__ final) {
    int n = blockIdx.x;
    int t = threadIdx.x;
    int lane = t & 63, wid = t >> 6;
    __shared__ unsigned int words[128];
    __shared__ int   pfx[128];
    __shared__ int   midx[MAXE];
    __shared__ float wts[MAXE];
    __shared__ float q0s[32];
    __shared__ float4 redv[4][32];
    __shared__ float  redw[4];

    unsigned int w = mask[n * 128 + t];
    words[t] = w;
    if (t < 32) q0s[t] = Q0[n * 32 + t];
    int p = __popc(w);
#pragma unroll
    for (int off = 1; off < 64; off <<= 1) {
        int y = __shfl_up(p, off);
        if (lane >= off) p += y;
    }
    pfx[t] = p;
    __syncthreads();
    if (wid == 1) pfx[t] = p + pfx[63];
    __syncthreads();
    int E = min(pfx[127], MAXE);

    for (int e = t; e < E; e += 128) {
        int lo = 0, hi = 127;
        while (lo < hi) { int mid = (lo + hi) >> 1; if (pfx[mid] > e) hi = mid; else lo = mid + 1; }
        int base = lo ? pfx[lo - 1] : 0;
        int r = e - base;
        unsigned int x = words[lo];
        for (int i = 0; i < r; ++i) x &= x - 1;
        int m = lo * 32 + (__ffs(x) - 1);
        const float4* kp = (const float4*)(K0 + m * 32);
        float s = 0.f;
#pragma unroll
        for (int i = 0; i < 8; ++i) {
            float4 kv = kp[i];
            s += q0s[i * 4 + 0] * kv.x + q0s[i * 4 + 1] * kv.y +
                 q0s[i * 4 + 2] * kv.z + q0s[i * 4 + 3] * kv.w;
        }
        wts[e]  = __expf(s * TEMP - 1.0f);
        midx[e] = m;
    }
    __syncthreads();

    int cg_ = t & 31, eg = t >> 5;
    const float4* V4 = (const float4*)V;
    float4 acc = {0.f, 0.f, 0.f, 0.f};
    float wp = 0.f;
    int e = eg;
    for (; e + 4 < E; e += 8) {
        float wa = wts[e];     int ma = midx[e];
        float wb = wts[e + 4]; int mb = midx[e + 4];
        float4 va = V4[ma * 32 + cg_];
        float4 vb = V4[mb * 32 + cg_];
        acc.x += wa * va.x + wb * vb.x; acc.y += wa * va.y + wb * vb.y;
        acc.z += wa * va.z + wb * vb.z; acc.w += wa * va.w + wb * vb.w;
        wp += wa + wb;
    }
    for (; e < E; e += 4) {
        float wt = wts[e];
        float4 v = V4[midx[e] * 32 + cg_];
        acc.x += wt * v.x; acc.y += wt * v.y; acc.z += wt * v.z; acc.w += wt * v.w;
        wp += wt;
    }
    redv[eg][cg_] = acc;
    if (cg_ == 0) redw[eg] = wp;
    __syncthreads();
    if (t < 32) {
        float4 a0 = redv[0][t], a1 = redv[1][t], a2 = redv[2][t], a3 = redv[3][t];
        float wsum = 1.0f + redw[0] + redw[1] + redw[2] + redw[3];
        float4 vd = V4[n * 32 + t];
        float4 bb = ((const float4*)bout)[t];
        float inv = 1.0f / wsum;
        float4 o;
        o.x = (a0.x + a1.x + a2.x + a3.x + vd.x) * inv + bb.x;
        o.y = (a0.y + a1.y + a2.y + a3.y + vd.y) * inv + bb.y;
        o.z = (a0.z + a1.z + a2.z + a3.z + vd.z) * inv + bb.z;
        o.w = (a0.w + a1.w + a2.w + a3.w + vd.w) * inv + bb.w;
        ((float4*)final)[n * 32 + t] = o;
    }
}

#define GT_PIX 64
__global__ void __launch_bounds__(256) gather_out(
    const float* __restrict__ final, const int* __restrict__ seg,
    float* __restrict__ out) {
    __shared__ __align__(16) float tile[GT_PIX][132];
    __shared__ int sseg[GT_PIX];
    int base = blockIdx.x * GT_PIX;
    int t = threadIdx.x;
    if (t < GT_PIX) sseg[t] = seg[base + t];
    __syncthreads();
    int c4 = t & 31, pp = t >> 5;
    const float4* f4 = (const float4*)final;
#pragma unroll
    for (int i = 0; i < 8; ++i) {
        int p = pp + 8 * i;
        float4 v = f4[sseg[p] * 32 + c4];
        *(float4*)&tile[p][c4 * 4] = v;
    }
    __syncthreads();
    int jp = t >> 4;
    int cg_ = t & 15;
#pragma unroll
    for (int pass = 0; pass < 8; ++pass) {
        int cc = cg_ + 16 * pass;
        float4 v;
        v.x = tile[4 * jp + 0][cc];
        v.y = tile[4 * jp + 1][cc];
        v.z = tile[4 * jp + 2][cc];
        v.w = tile[4 * jp + 3][cc];
        *(float4*)(out + (size_t)cc * (HW * HW) + base + 4 * jp) = v;
    }
}

extern "C" void kernel_launch(void* const* d_in, const int* in_sizes, int n_in,
                              void* d_out, int out_size, void* d_ws, size_t ws_size,
                              hipStream_t stream) {
    const float* spf  = (const float*)d_in[0];   // (128, 4096)
    const int*   seg  = (const int*)d_in[1];     // (512, 512)
    const float* wqkv = (const float*)d_in[2];   // (128, 384)
    const float* wout = (const float*)d_in[3];   // (128, 128)
    const float* bout = (const float*)d_in[4];   // (128,)
    float* out = (float*)d_out;                  // (1,128,512,512)

    char* ws = (char*)d_ws;                      // ~7.1 MB used
    unsigned int* mask = (unsigned int*)ws;                     // 2 MB
    float* Q0  = (float*)(ws + (2u << 20));                     // 512 KB
    float* K0  = (float*)(ws + (2u << 20) + (512u << 10));      // 512 KB
    float* Vp  = (float*)(ws + (3u << 20));                     // 2 MB (= x @ Wfused)
    float* fin = (float*)(ws + (5u << 20));                     // 2 MB
    float* Wf  = (float*)(ws + (7u << 20));                     // 64 KB

    void* args[12];
    args[0] = (void*)&seg;  args[1] = (void*)&spf;  args[2] = (void*)&wqkv;
    args[3] = (void*)&wout; args[4] = (void*)&bout; args[5] = (void*)&out;
    args[6] = (void*)&mask; args[7] = (void*)&Q0;   args[8] = (void*)&K0;
    args[9] = (void*)&Vp;   args[10] = (void*)&fin; args[11] = (void*)&Wf;

    hipError_t err = hipLaunchCooperativeKernel((const void*)fused_all,
                                                dim3(GRID), dim3(NTHR),
                                                args, 0, stream);
    if (err != hipSuccess) {
        (void)hipGetLastError();                 // clear sticky error
        hipLaunchKernelGGL(prep, dim3(PREP_ZERO + PREP_WF), dim3(256), 0, stream,
                           mask, wqkv, wout, Wf);
        hipLaunchKernelGGL(adj_qkv, dim3(ADJ_BLOCKS + QKV_BLOCKS), dim3(256), 0, stream,
                           seg, mask, spf, wqkv, Wf, Q0, K0, Vp);
        hipLaunchKernelGGL(sparse_attn, dim3(4096), dim3(128), 0, stream,
                           mask, Q0, K0, Vp, bout, fin);
        hipLaunchKernelGGL(gather_out, dim3((HW * HW) / GT_PIX), dim3(256), 0, stream,
                           fin, seg, out);
    }
}